// Round 6
// baseline (105.751 us; speedup 1.0000x reference)
//
#include <hip/hip_runtime.h>

// Depthwise 41-tap separable gaussian blur of flow = noise*2-1.
// [16, 512, 512, 2] fp32, SAME zero padding.
//
// R10: R9 (full-width fused, FTY=8, 4 blocks/CU = 32 waves/CU) minus the
// output LDS transpose. Phase-2 thread (y, xg) already holds 8 CONSECUTIVE
// output cols of row y0+y, so it stores them directly as 4x float4 (16B
// aligned; a wave's 4 store instructions tile complete 128B lines, merged
// in L2). This removes 2 of the 3 __syncthreads, 8 LDS writes + 8 LDS
// reads per thread, and the out-stage LDS region. Remaining structure is
// the compulsory minimum: dense loads + vertical FMA -> 1 barrier ->
// LDS reads + horizontal FMA -> dense stores.
//
// Session invariants (hard-won):
//  - __launch_bounds__ min_waves=8 caps the allocator at 32 VGPRs
//    (256/min_waves, NOT 512/min_waves) and force-spills acc[] to scratch
//    (R5, R8: VGPR_Count=32, WRITE_SIZE ~3x output, 2-6x slowdown).
//    Keep (512, 4); actual usage <=64 VGPR gives 8 waves/SIMD anyway.
//  - 35.4KB LDS -> 4 blocks/CU; grid 1024 = exactly 4/CU.
//  - XCD-chunk swizzle: each XCD owns 128 consecutive (y-tile,batch)
//    slots = 2 whole images (~4.2MB ~ its 4MB L2), all co-resident, so
//    the 40-row vertical halo re-reads (6x request amplification) are
//    local-L2 hits: R7 measured FETCH 39MB ~ compulsory 33.5MB + eps.
//  - SSTR=553 keeps phase-2 b64 LDS reads at the wave64 8-byte floor
//    (uniform 4 lanes/bank-pair, SQ_LDS_BANK_CONFLICT ~ 4096/dispatch).
#define NB   16
#define H    512
#define W    512
#define KW   41
#define HALO 20

#define FTY   8                   // output rows per block
#define FROWS (FTY + KW - 1)      // 48 input rows loaded
#define SSTR  553                 // mid row stride (float2): 512 + 40 pad + 1
#define HPX   8                   // horizontal outputs per thread

// Raw gaussian taps exp(-d^2/50), d=-20..20; (1/sum)^2 folded into INV_S2.
constexpr float G[KW] = {
  0.0003354626f, 0.0007318024f, 0.0015338104f, 0.0030887172f,
  0.0059760229f, 0.0111089965f, 0.0198410947f, 0.0340474548f,
  0.0561347628f, 0.0889216176f, 0.1353352832f, 0.1978986990f,
  0.2780373005f, 0.3753110988f, 0.4867522560f, 0.6065306597f,
  0.7261490371f, 0.8352702114f, 0.9231163464f, 0.9801986733f,
  1.0f,
  0.9801986733f, 0.9231163464f, 0.8352702114f, 0.7261490371f,
  0.6065306597f, 0.4867522560f, 0.3753110988f, 0.2780373005f,
  0.1978986990f, 0.1353352832f, 0.0889216176f, 0.0561347628f,
  0.0340474548f, 0.0198410947f, 0.0111089965f, 0.0059760229f,
  0.0030887172f, 0.0015338104f, 0.0007318024f, 0.0003354626f
};

constexpr float gsum() { float s = 0.f; for (int i = 0; i < KW; ++i) s += G[i]; return s; }
constexpr float INV_S2 = 1.0f / (gsum() * gsum());

__global__ __launch_bounds__(512, 4)   // 128-VGPR cap; actual <=64 -> 8 waves/SIMD
void randflow_fused_kernel(const float* __restrict__ noise, float* __restrict__ out) {
    __shared__ float2 smem[FTY * SSTR];   // 4424 float2 = 35392 B -> 4 blocks/CU

    const int tid = threadIdx.x;          // 0..511 = x column

    // grid (64, 16) -> 1024 blocks; physical id dispatches to XCD id%8.
    // Bijective chunk swizzle: sid = (id&7)*128 + id/8.
    int id = blockIdx.x + 64 * blockIdx.y;
    id = ((id & 7) << 7) | (id >> 3);
    const int ly = id & 63;               // 64 y-tiles of 8 rows
    const int lb = id >> 6;               // 16 batches
    const int y0 = ly * FTY;

    // zero the 20-col left/right borders of all 8 LDS rows (image zero-pad)
    if (tid < FTY * 2 * HALO) {                   // 320 < 512: one step
        const int row = tid / 40;                 // const divide -> magic mul
        const int c   = tid - row * 40;
        const int col = (c < HALO) ? c : (c + W); // [0,20) U [532,552)
        smem[row * SSTR + col] = make_float2(0.f, 0.f);
    }

    // ---- phase 1: vertical 41-tap conv on flow = noise*2-1.
    // Thread = column tid, both channels as float2; 48 dense 4KB wave-row
    // loads; zero-pad in y via select on clamped (always-legal) addresses.
    {
        const float* __restrict__ src = noise + ((size_t)lb * H * W + tid) * 2;
        float2 acc[FTY];
        #pragma unroll
        for (int p = 0; p < FTY; ++p) acc[p] = make_float2(0.f, 0.f);

        const int ysb = y0 - HALO;
        #pragma unroll
        for (int j = 0; j < FROWS; ++j) {         // 48 rows
            const int ys = ysb + j;
            const int cy = min(max(ys, 0), H - 1);
            const float a  = (ys == cy) ? 2.0f : 0.0f;   // y-validity select
            const float bb = (ys == cy) ? -1.0f : 0.0f;
            const float2 u = *(const float2*)(src + (size_t)cy * (W * 2));
            float2 v;
            v.x = __builtin_fmaf(u.x, a, bb);
            v.y = __builtin_fmaf(u.y, a, bb);
            #pragma unroll
            for (int p = 0; p < FTY; ++p) {
                const int t = j - p;              // compile-time after unroll
                if (t >= 0 && t < KW) {
                    acc[p].x = __builtin_fmaf(G[t], v.x, acc[p].x);
                    acc[p].y = __builtin_fmaf(G[t], v.y, acc[p].y);
                }
            }
        }
        #pragma unroll
        for (int p = 0; p < FTY; ++p)             // lanes dense along x
            smem[p * SSTR + HALO + tid] = acc[p];
    }
    __syncthreads();   // the only barrier: P1 LDS writes -> P2 LDS reads

    // ---- phase 2: horizontal 41-tap conv in LDS, sliding window.
    // Thread = (row y, 8-col group xg); 48 reads per 8 outputs.
    // Banks: (18y + 16(xg&1) + 2j) mod 32 -> 16 distinct even residues,
    // uniform 4 lanes/bank-pair = the wave64 8-byte floor (conflict-free).
    const int y  = tid & 7;
    const int xg = tid >> 3;                      // 0..63
    const int x0 = xg * HPX;
    float2 facc[HPX];
    #pragma unroll
    for (int p = 0; p < HPX; ++p) facc[p] = make_float2(0.f, 0.f);
    #pragma unroll
    for (int j = 0; j < HPX + KW - 1; ++j) {      // 48 padded cols x0..x0+47
        const float2 v = smem[y * SSTR + x0 + j];
        #pragma unroll
        for (int p = 0; p < HPX; ++p) {
            const int t = j - p;
            if (t >= 0 && t < KW) {
                facc[p].x = __builtin_fmaf(G[t], v.x, facc[p].x);
                facc[p].y = __builtin_fmaf(G[t], v.y, facc[p].y);
            }
        }
    }

    // ---- direct stores: thread owns cols x0..x0+7 of row y0+y -> 4x
    // float4 at +0,16,32,48 B (base = xg*64 B, 16B-aligned). A wave's 4
    // store instructions tile complete 128B lines (merged in L2).
    float* __restrict__ ob = out + (((size_t)lb * H + y0 + y) * W + x0) * 2;
    #pragma unroll
    for (int k = 0; k < 4; ++k) {
        float4 r;
        r.x = facc[2 * k].x     * INV_S2;
        r.y = facc[2 * k].y     * INV_S2;
        r.z = facc[2 * k + 1].x * INV_S2;
        r.w = facc[2 * k + 1].y * INV_S2;
        *(float4*)(ob + k * 4) = r;
    }
}

extern "C" void kernel_launch(void* const* d_in, const int* in_sizes, int n_in,
                              void* d_out, int out_size, void* d_ws, size_t ws_size,
                              hipStream_t stream) {
    // d_in[0] = inputs [16,512,512,1]  -- UNUSED by the reference
    // d_in[1] = rand_noise [16,512,512,2] fp32
    const float* noise = (const float*)d_in[1];
    float* out = (float*)d_out;

    randflow_fused_kernel<<<dim3(H / FTY, NB), dim3(512), 0, stream>>>(noise, out);
}

// Round 7
// 103.063 us; speedup vs baseline: 1.0261x; 1.0261x over previous
//
#include <hip/hip_runtime.h>

// Depthwise 41-tap separable gaussian blur of flow = noise*2-1.
// [16, 512, 512, 2] fp32, SAME zero padding.
//
// R11 = R9 (best-measured config of the session, bench 102.06us): full-width
// fused kernel, FTY=8, 4 blocks/CU = 32 waves/CU, LDS out-stage transpose
// for full-128B-line dense stores. R10's direct-store variant (1 barrier,
// scattered 16B/64B-stride stores) measured 105.75 -- the wave-level store
// density is worth more than the two barriers it costs. Single-barrier +
// dense stores is geometrically impossible (each thread owns 64 contiguous
// output bytes), and a non-aliased out-stage (to drop the middle barrier)
// needs 68KB LDS -> 2 blocks/CU, the R7 failure mode.
//
// Session invariants (hard-won):
//  - __launch_bounds__ min_waves=8 caps the allocator at 32 VGPRs
//    (256/min_waves, NOT 512/min_waves) and force-spills acc[] to scratch
//    (R5, R8: VGPR_Count=32, WRITE_SIZE ~3x output, 2-6x slowdown).
//    Keep (512, 4); actual usage <=64 VGPR gives 8 waves/SIMD anyway.
//  - 35.4KB LDS -> 4 blocks/CU; grid 1024 = exactly 4/CU.
//  - XCD-chunk swizzle: each XCD owns 128 consecutive (y-tile,batch)
//    slots = 2 whole images (~4.2MB ~ its 4MB L2), all co-resident, so
//    the 40-row vertical halo re-reads (6x request amplification) are
//    local-L2 hits (R7 measured FETCH 39MB ~ compulsory 33.5MB + eps).
//  - SSTR=553 / OSTR=513 keep all LDS phases at the wave64 8-byte floor
//    (uniform 4 lanes/bank-pair; SQ_LDS_BANK_CONFLICT ~4096/dispatch).
// Floors: 688M FMA = 8.75us VALU; 67MB compulsory HBM = 10.6us. Kernel is
// below the 41us profiling visibility threshold and within bench noise of
// these floors.
#define NB   16
#define H    512
#define W    512
#define KW   41
#define HALO 20

#define FTY   8                   // output rows per block
#define FROWS (FTY + KW - 1)      // 48 input rows loaded
#define SSTR  553                 // mid row stride (float2): 512 + 40 pad + 1
#define OSTR  513                 // out-stage row stride (float2)
#define HPX   8                   // horizontal outputs per thread

// Raw gaussian taps exp(-d^2/50), d=-20..20; (1/sum)^2 folded into INV_S2.
constexpr float G[KW] = {
  0.0003354626f, 0.0007318024f, 0.0015338104f, 0.0030887172f,
  0.0059760229f, 0.0111089965f, 0.0198410947f, 0.0340474548f,
  0.0561347628f, 0.0889216176f, 0.1353352832f, 0.1978986990f,
  0.2780373005f, 0.3753110988f, 0.4867522560f, 0.6065306597f,
  0.7261490371f, 0.8352702114f, 0.9231163464f, 0.9801986733f,
  1.0f,
  0.9801986733f, 0.9231163464f, 0.8352702114f, 0.7261490371f,
  0.6065306597f, 0.4867522560f, 0.3753110988f, 0.2780373005f,
  0.1978986990f, 0.1353352832f, 0.0889216176f, 0.0561347628f,
  0.0340474548f, 0.0198410947f, 0.0111089965f, 0.0059760229f,
  0.0030887172f, 0.0015338104f, 0.0007318024f, 0.0003354626f
};

constexpr float gsum() { float s = 0.f; for (int i = 0; i < KW; ++i) s += G[i]; return s; }
constexpr float INV_S2 = 1.0f / (gsum() * gsum());

__global__ __launch_bounds__(512, 4)   // 128-VGPR cap; actual <=64 -> 8 waves/SIMD
void randflow_fused_kernel(const float* __restrict__ noise, float* __restrict__ out) {
    __shared__ float2 smem[FTY * SSTR];   // 4424 float2 = 35392 B -> 4 blocks/CU

    const int tid = threadIdx.x;          // 0..511 = x column

    // grid (64, 16) -> 1024 blocks; physical id dispatches to XCD id%8.
    // Bijective chunk swizzle: sid = (id&7)*128 + id/8.
    int id = blockIdx.x + 64 * blockIdx.y;
    id = ((id & 7) << 7) | (id >> 3);
    const int ly = id & 63;               // 64 y-tiles of 8 rows
    const int lb = id >> 6;               // 16 batches
    const int y0 = ly * FTY;

    // zero the 20-col left/right borders of all 8 LDS rows (image zero-pad)
    if (tid < FTY * 2 * HALO) {                   // 320 < 512: one step
        const int row = tid / 40;                 // const divide -> magic mul
        const int c   = tid - row * 40;
        const int col = (c < HALO) ? c : (c + W); // [0,20) U [532,552)
        smem[row * SSTR + col] = make_float2(0.f, 0.f);
    }

    // ---- phase 1: vertical 41-tap conv on flow = noise*2-1.
    // Thread = column tid, both channels as float2; 48 dense 4KB wave-row
    // loads; zero-pad in y via select on clamped (always-legal) addresses.
    {
        const float* __restrict__ src = noise + ((size_t)lb * H * W + tid) * 2;
        float2 acc[FTY];
        #pragma unroll
        for (int p = 0; p < FTY; ++p) acc[p] = make_float2(0.f, 0.f);

        const int ysb = y0 - HALO;
        #pragma unroll
        for (int j = 0; j < FROWS; ++j) {         // 48 rows
            const int ys = ysb + j;
            const int cy = min(max(ys, 0), H - 1);
            const float a  = (ys == cy) ? 2.0f : 0.0f;   // y-validity select
            const float bb = (ys == cy) ? -1.0f : 0.0f;
            const float2 u = *(const float2*)(src + (size_t)cy * (W * 2));
            float2 v;
            v.x = __builtin_fmaf(u.x, a, bb);
            v.y = __builtin_fmaf(u.y, a, bb);
            #pragma unroll
            for (int p = 0; p < FTY; ++p) {
                const int t = j - p;              // compile-time after unroll
                if (t >= 0 && t < KW) {
                    acc[p].x = __builtin_fmaf(G[t], v.x, acc[p].x);
                    acc[p].y = __builtin_fmaf(G[t], v.y, acc[p].y);
                }
            }
        }
        #pragma unroll
        for (int p = 0; p < FTY; ++p)             // lanes dense along x
            smem[p * SSTR + HALO + tid] = acc[p];
    }
    __syncthreads();

    // ---- phase 2: horizontal 41-tap conv in LDS, sliding window.
    // Thread = (row y, 8-col group xg); 48 reads per 8 outputs.
    // Banks: (18y + 16(xg&1) + 2j) mod 32 -> 16 distinct even residues,
    // uniform 4 lanes/bank-pair = the wave64 8-byte floor (conflict-free).
    const int y  = tid & 7;
    const int xg = tid >> 3;                      // 0..63
    const int x0 = xg * HPX;
    float2 facc[HPX];
    {
        #pragma unroll
        for (int p = 0; p < HPX; ++p) facc[p] = make_float2(0.f, 0.f);
        #pragma unroll
        for (int j = 0; j < HPX + KW - 1; ++j) {  // 48 padded cols x0..x0+47
            const float2 v = smem[y * SSTR + x0 + j];
            #pragma unroll
            for (int p = 0; p < HPX; ++p) {
                const int t = j - p;
                if (t >= 0 && t < KW) {
                    facc[p].x = __builtin_fmaf(G[t], v.x, facc[p].x);
                    facc[p].y = __builtin_fmaf(G[t], v.y, facc[p].y);
                }
            }
        }
    }
    __syncthreads();   // all phase-2 reads done; safe to overwrite alias

    // out-stage (aliases smem): scaled results, transpose-friendly layout
    #pragma unroll
    for (int p = 0; p < HPX; ++p) {
        float2 r;
        r.x = facc[p].x * INV_S2;
        r.y = facc[p].y * INV_S2;
        smem[y * OSTR + x0 + p] = r;
    }
    __syncthreads();

    // ---- phase 3: 8 dense full-row 4KB stores, lanes dense along x.
    float* __restrict__ ob = out + (((size_t)lb * H + y0) * W) * 2;
    #pragma unroll
    for (int k = 0; k < FTY; ++k)
        *(float2*)(ob + (size_t)k * (W * 2) + tid * 2) = smem[k * OSTR + tid];
}

extern "C" void kernel_launch(void* const* d_in, const int* in_sizes, int n_in,
                              void* d_out, int out_size, void* d_ws, size_t ws_size,
                              hipStream_t stream) {
    // d_in[0] = inputs [16,512,512,1]  -- UNUSED by the reference
    // d_in[1] = rand_noise [16,512,512,2] fp32
    const float* noise = (const float*)d_in[1];
    float* out = (float*)d_out;

    randflow_fused_kernel<<<dim3(H / FTY, NB), dim3(512), 0, stream>>>(noise, out);
}